// Round 1
// baseline (1022.235 us; speedup 1.0000x reference)
//
#include <hip/hip_runtime.h>
#include <cstdint>
#include <cstddef>

#define V 50257
#define BLOCK 256

__device__ __forceinline__ void combine(float& m, float& s, float mo, float so) {
    float m2 = fmaxf(m, mo);
    s = s * __expf(m - m2) + so * __expf(mo - m2);
    m = m2;
}

__global__ __launch_bounds__(BLOCK) void sce_row_kernel(
    const float* __restrict__ inputs, const int* __restrict__ targets,
    float* __restrict__ row_out) {
    const int row = blockIdx.x;
    const int tid = threadIdx.x;
    const float* row_ptr = inputs + (size_t)row * V;

    // target gather (thread 0 only; issued early, tiny traffic)
    float xt = 0.0f;
    if (tid == 0) xt = row_ptr[targets[row]];

    // alignment: row start address mod 16 B rotates per row (V % 4 == 1)
    const int misalign = (int)(((size_t)row * V) & 3);
    const int head = (4 - misalign) & 3;
    const int nvec = (V - head) >> 2;
    const int tail_start = head + (nvec << 2);
    const float4* vp = reinterpret_cast<const float4*>(row_ptr + head);

    // online softmax accumulation: one exp-rescale per float4
    float m = -INFINITY, s = 0.0f;
    for (int i = tid; i < nvec; i += BLOCK) {
        float4 v = vp[i];
        float mv = fmaxf(fmaxf(v.x, v.y), fmaxf(v.z, v.w));
        float m2 = fmaxf(m, mv);
        s = s * __expf(m - m2)
          + __expf(v.x - m2) + __expf(v.y - m2)
          + __expf(v.z - m2) + __expf(v.w - m2);
        m = m2;
    }
    // head scalars (<=3)
    for (int i = tid; i < head; i += BLOCK) {
        float v = row_ptr[i];
        float m2 = fmaxf(m, v);
        s = s * __expf(m - m2) + __expf(v - m2);
        m = m2;
    }
    // tail scalars (<=3)
    for (int i = tail_start + tid; i < V; i += BLOCK) {
        float v = row_ptr[i];
        float m2 = fmaxf(m, v);
        s = s * __expf(m - m2) + __expf(v - m2);
        m = m2;
    }
    // NB: nvec (~12564) >= BLOCK, so every thread has finite m here (no -inf NaN hazard)

    // wave (64-lane) butterfly reduce
    for (int off = 32; off > 0; off >>= 1) {
        float mo = __shfl_xor(m, off, 64);
        float so = __shfl_xor(s, off, 64);
        combine(m, s, mo, so);
    }
    __shared__ float sm[BLOCK / 64], ss[BLOCK / 64];
    const int wave = tid >> 6;
    const int lane = tid & 63;
    if (lane == 0) { sm[wave] = m; ss[wave] = s; }
    __syncthreads();
    if (tid == 0) {
        m = sm[0]; s = ss[0];
        #pragma unroll
        for (int w = 1; w < BLOCK / 64; ++w) combine(m, s, sm[w], ss[w]);
        const float log_scale = logf((float)(1.0 - 0.154 + 0.154 / (double)V));
        // logp_t + log(scale)
        row_out[row] = (xt - m - logf(s)) + log_scale;
    }
}

__global__ __launch_bounds__(BLOCK) void sce_final_kernel(
    const float* __restrict__ row_vals, float* __restrict__ out, int n) {
    float sum = 0.0f;
    for (int i = threadIdx.x; i < n; i += BLOCK) sum += row_vals[i];
    for (int off = 32; off > 0; off >>= 1) sum += __shfl_xor(sum, off, 64);
    __shared__ float ssum[BLOCK / 64];
    const int wave = threadIdx.x >> 6;
    const int lane = threadIdx.x & 63;
    if (lane == 0) ssum[wave] = sum;
    __syncthreads();
    if (threadIdx.x == 0) {
        float t = 0.0f;
        #pragma unroll
        for (int w = 0; w < BLOCK / 64; ++w) t += ssum[w];
        out[0] = -t / (float)n;
    }
}

extern "C" void kernel_launch(void* const* d_in, const int* in_sizes, int n_in,
                              void* d_out, int out_size, void* d_ws, size_t ws_size,
                              hipStream_t stream) {
    const float* inputs = (const float*)d_in[0];
    const int* targets = (const int*)d_in[1];
    float* out = (float*)d_out;
    const int n = in_sizes[1];          // 4096 rows
    float* row_vals = (float*)d_ws;     // n floats of scratch (ws is re-poisoned; fully overwritten by kernel 1)

    sce_row_kernel<<<n, BLOCK, 0, stream>>>(inputs, targets, row_vals);
    sce_final_kernel<<<1, BLOCK, 0, stream>>>(row_vals, out, n);
}